// Round 19
// baseline (150.139 us; speedup 1.0000x reference)
//
#include <hip/hip_runtime.h>
#include <hip/hip_bf16.h>

#define ALPHA_V 0.99f
#define TH_HID 0.1f
#define TH_LAST 1.0e5f

static constexpr int B_ = 32, T_ = 300, CIN_ = 2312;
static constexpr int KP1 = 2336;          // CIN padded to 73*32
static constexpr int M_ = 9600;           // B*T

using short8 = __attribute__((ext_vector_type(8))) short;
using f32x4  = __attribute__((ext_vector_type(4))) float;

__device__ __forceinline__ float bf16bits_to_f(ushort u) {
    union { unsigned int i; float f; } cv; cv.i = ((unsigned int)u) << 16; return cv.f;
}
__device__ __forceinline__ ushort f_to_bf16bits(float f) {
    __hip_bfloat16 h = __float2bfloat16(f);
    return *(ushort*)&h;
}

// ---------------------------------------------------------------------------
// Weight split for ALL layers in one launch: W f32 [N][K] -> Whi/Wlo bf16
// ---------------------------------------------------------------------------
__global__ void prep_w_all(
    const float* __restrict__ Wa, ushort* __restrict__ WaHi, ushort* __restrict__ WaLo, int Na, int Ka, int Kpa,
    const float* __restrict__ Wb, ushort* __restrict__ WbHi, ushort* __restrict__ WbLo, int Nb, int Kb, int Kpb,
    const float* __restrict__ Wc, ushort* __restrict__ WcHi, ushort* __restrict__ WcLo, int Nc, int Kc, int Kpc)
{
    int idx = blockIdx.x * 256 + threadIdx.x;
    const int ea = Na * Kpa, eb = Nb * Kpb, ec = Nc * Kpc;
    const float* W; ushort *Whi, *Wlo; int K, Kp;
    if (idx < ea) {
        W = Wa; Whi = WaHi; Wlo = WaLo; K = Ka; Kp = Kpa;
    } else if ((idx -= ea) < eb) {
        W = Wb; Whi = WbHi; Wlo = WbLo; K = Kb; Kp = Kpb;
    } else if ((idx -= eb) < ec) {
        W = Wc; Whi = WcHi; Wlo = WcLo; K = Kc; Kp = Kpc;
    } else return;
    int n = idx / Kp, k = idx % Kp;
    float w = (k < K) ? W[(size_t)n * K + k] : 0.f;
    __hip_bfloat16 hi = __float2bfloat16(w);
    float hif = __bfloat162float(hi);
    __hip_bfloat16 lo = __float2bfloat16(w - hif);
    Whi[idx] = *(ushort*)&hi;
    Wlo[idx] = *(ushort*)&lo;
}

// ---------------------------------------------------------------------------
// Layer-1 GEMM with FUSED transpose+bf16 convert of X.
// X f32 [B][CIN][T] (t contiguous).  P[split][b*T+t][64] f32 partials.
// Block: 64 t x 64 o tile, fixed b.  BK=32, double-buffered LDS, 4 waves 2x2.
// grid (5 t-tiles, 4 splits, 32 b).
// ---------------------------------------------------------------------------
__global__ __launch_bounds__(256) void gemm1_fused(
    const float* __restrict__ X, const ushort* __restrict__ Whi,
    const ushort* __restrict__ Wlo, float* __restrict__ P)
{
    constexpr int LP = 40;
    __shared__ ushort As[2][64 * LP];
    __shared__ ushort Bh[2][64 * LP];
    __shared__ ushort Bl[2][64 * LP];

    const int tid = threadIdx.x;
    const int t0 = blockIdx.x * 64;
    const int split = blockIdx.y;
    const int b = blockIdx.z;
    const int stepBeg = split * 19;                 // 73 steps: 19/19/19/16
    const int nSteps = min(19, 73 - stepBeg);
    const int tvalid = min(64, T_ - t0);
    float* Z = P + (size_t)split * M_ * 64;

    const int wid = tid >> 6, lane = tid & 63;
    const int wm = (wid >> 1) * 32, wn = (wid & 1) * 32;
    const int lr = lane & 15, lk = (lane >> 4) * 8;

    f32x4 acc[2][2];
    {
        f32x4 z4 = {0.f, 0.f, 0.f, 0.f};
        acc[0][0] = z4; acc[0][1] = z4; acc[1][0] = z4; acc[1][1] = z4;
    }

    const int p = tid >> 4;                         // k-pair 0..15
    const int tq = tid & 15;                        // t-quad
    const bool tok = (tq * 4 < tvalid);
    const float* Xb = X + (size_t)b * CIN_ * T_ + t0 + tq * 4;

    const int sr = tid >> 2, sq = (tid & 3) * 8;
    const ushort* Hp = Whi + (size_t)sr * KP1 + (size_t)stepBeg * 32 + sq;
    const ushort* Lp = Wlo + (size_t)sr * KP1 + (size_t)stepBeg * 32 + sq;
    const int sdstW = sr * LP + sq;

    f32x4 xa, xb;
    uint4 rh, rl;

    auto loadStep = [&](int s) {
        int gk = (stepBeg + s) * 32 + 2 * p;
        f32x4 z4 = {0.f, 0.f, 0.f, 0.f};
        xa = z4; xb = z4;
        if (tok) {
            if (gk < CIN_)     xa = *(const f32x4*)&Xb[(size_t)gk * T_];
            if (gk + 1 < CIN_) xb = *(const f32x4*)&Xb[(size_t)(gk + 1) * T_];
        }
        rh = *(const uint4*)(Hp + (size_t)s * 32);
        rl = *(const uint4*)(Lp + (size_t)s * 32);
    };
    auto writeStep = [&](int bufi) {
#pragma unroll
        for (int j = 0; j < 4; ++j) {
            uint u = (uint)f_to_bf16bits(xa[j]) | ((uint)f_to_bf16bits(xb[j]) << 16);
            *(uint*)&As[bufi][(tq * 4 + j) * LP + 2 * p] = u;
        }
        *(uint4*)&Bh[bufi][sdstW] = rh;
        *(uint4*)&Bl[bufi][sdstW] = rl;
    };

    loadStep(0);
    writeStep(0);
    for (int s = 0; s < nSteps; ++s) {
        const int cur = s & 1, nxt = cur ^ 1;
        if (s + 1 < nSteps) loadStep(s + 1);        // global loads overlap barrier+MFMA
        __syncthreads();                            // buf[cur] visible

        short8 af[2], bhf[2], blf[2];
#pragma unroll
        for (int i = 0; i < 2; ++i) {
            af[i]  = *(const short8*)&As[cur][(wm + i * 16 + lr) * LP + lk];
            bhf[i] = *(const short8*)&Bh[cur][(wn + i * 16 + lr) * LP + lk];
            blf[i] = *(const short8*)&Bl[cur][(wn + i * 16 + lr) * LP + lk];
        }
#pragma unroll
        for (int i = 0; i < 2; ++i)
#pragma unroll
            for (int j = 0; j < 2; ++j) {
                acc[i][j] = __builtin_amdgcn_mfma_f32_16x16x32_bf16(af[i], bhf[j], acc[i][j], 0, 0, 0);
                acc[i][j] = __builtin_amdgcn_mfma_f32_16x16x32_bf16(af[i], blf[j], acc[i][j], 0, 0, 0);
            }
        if (s + 1 < nSteps) writeStep(nxt);
    }

    // C/D: col = lane&15, row = (lane>>4)*4 + r
    const int orow = (lane >> 4) * 4;
#pragma unroll
    for (int i = 0; i < 2; ++i)
#pragma unroll
        for (int j = 0; j < 2; ++j)
#pragma unroll
            for (int r = 0; r < 4; ++r) {
                int tl = wm + i * 16 + orow + r;
                if (tl < tvalid)
                    Z[(size_t)(b * T_ + t0 + tl) * 64 + (wn + j * 16 + lr)] = acc[i][j][r];
            }
}

// ---------------------------------------------------------------------------
// MFMA GEMM 64x64 tile, BK=32, double-buffered LDS (layers 2, 3).
// Separate-kernel structure beats GEMM+scan fusion here (R15/R16 measured).
// ---------------------------------------------------------------------------
__global__ __launch_bounds__(256) void gemm_mfma64(
    const ushort* __restrict__ A, const ushort* __restrict__ Whi,
    const ushort* __restrict__ Wlo, float* __restrict__ Z,
    int lda, int ldz, int nSteps)
{
    constexpr int LP = 40;
    __shared__ ushort As[2][64 * LP];
    __shared__ ushort Bh[2][64 * LP];
    __shared__ ushort Bl[2][64 * LP];

    const int tid = threadIdx.x;
    const int m0 = blockIdx.x * 64, n0 = blockIdx.y * 64;

    const int wid = tid >> 6, lane = tid & 63;
    const int wm = (wid >> 1) * 32, wn = (wid & 1) * 32;
    const int lr = lane & 15, lk = (lane >> 4) * 8;

    f32x4 acc[2][2];
    {
        f32x4 z4 = {0.f, 0.f, 0.f, 0.f};
        acc[0][0] = z4; acc[0][1] = z4; acc[1][0] = z4; acc[1][1] = z4;
    }

    const int sr = tid >> 2, sq = (tid & 3) * 8;
    const ushort* Ap = A   + (size_t)(m0 + sr) * lda + sq;
    const ushort* Hp = Whi + (size_t)(n0 + sr) * lda + sq;
    const ushort* Lp = Wlo + (size_t)(n0 + sr) * lda + sq;
    const int sdst = sr * LP + sq;

    uint4 ra = *(const uint4*)(Ap);
    uint4 rh = *(const uint4*)(Hp);
    uint4 rl = *(const uint4*)(Lp);
    *(uint4*)&As[0][sdst] = ra;
    *(uint4*)&Bh[0][sdst] = rh;
    *(uint4*)&Bl[0][sdst] = rl;

    for (int s = 0; s < nSteps; ++s) {
        const int cur = s & 1, nxt = cur ^ 1;
        if (s + 1 < nSteps) {
            ra = *(const uint4*)(Ap + (size_t)(s + 1) * 32);
            rh = *(const uint4*)(Hp + (size_t)(s + 1) * 32);
            rl = *(const uint4*)(Lp + (size_t)(s + 1) * 32);
        }
        __syncthreads();

        short8 af[2], bhf[2], blf[2];
#pragma unroll
        for (int i = 0; i < 2; ++i) {
            af[i]  = *(const short8*)&As[cur][(wm + i * 16 + lr) * LP + lk];
            bhf[i] = *(const short8*)&Bh[cur][(wn + i * 16 + lr) * LP + lk];
            blf[i] = *(const short8*)&Bl[cur][(wn + i * 16 + lr) * LP + lk];
        }
#pragma unroll
        for (int i = 0; i < 2; ++i)
#pragma unroll
            for (int j = 0; j < 2; ++j) {
                acc[i][j] = __builtin_amdgcn_mfma_f32_16x16x32_bf16(af[i], bhf[j], acc[i][j], 0, 0, 0);
                acc[i][j] = __builtin_amdgcn_mfma_f32_16x16x32_bf16(af[i], blf[j], acc[i][j], 0, 0, 0);
            }
        if (s + 1 < nSteps) {
            *(uint4*)&As[nxt][sdst] = ra;
            *(uint4*)&Bh[nxt][sdst] = rh;
            *(uint4*)&Bl[nxt][sdst] = rl;
        }
    }

    const int orow = (lane >> 4) * 4;
#pragma unroll
    for (int i = 0; i < 2; ++i)
#pragma unroll
        for (int j = 0; j < 2; ++j)
#pragma unroll
            for (int r = 0; r < 4; ++r)
                Z[(size_t)(m0 + wm + i * 16 + orow + r) * ldz + (n0 + wn + j * 16 + lr)]
                    = acc[i][j][r];
}

// ---------------------------------------------------------------------------
// CUBA-LIF scan, thread per neuron, chunked register double-buffer prefetch.
// CH=10 proven at default occupancy (R8/R14).  NEW: __launch_bounds__(64, 1)
// tells the allocator only 1 wave/SIMD is needed (TLP is problem-capped at
// <=1 wave/CU for these scans), licensing a big VGPR budget so CH=20's
// 2x20-float double-buffer can stay register-resident (R10/R11's CH>=20
// failures showed VGPR pinned at 28 without this declaration).
// ---------------------------------------------------------------------------
#define LOADC(buf, t0)                                                       \
    _Pragma("unroll")                                                        \
    for (int j = 0; j < CH; ++j) {                                           \
        float sacc = zp[(size_t)((t0) + j) * C];                             \
        _Pragma("unroll")                                                    \
        for (int k = 1; k < NS; ++k)                                         \
            sacc += zp[(size_t)k * splitStride + (size_t)((t0) + j) * C];    \
        buf[j] = sacc;                                                       \
    }
#define SCANC(buf, t0)                                                       \
    _Pragma("unroll")                                                        \
    for (int j = 0; j < CH; ++j) {                                           \
        v = ALPHA_V * v + buf[j];                                            \
        bool sp = (v >= th);                                                 \
        op[(size_t)((t0) + j) * C] = sp ? (ushort)0x3F80 : (ushort)0;        \
        v = sp ? 0.f : v;                                                    \
    }

template<int NS, int CH>
__global__ __launch_bounds__(64, 1) void scan_tpn2(
    const float* __restrict__ z, ushort* __restrict__ out,
    int shiftC, size_t splitStride, float th)
{
    const int C = 1 << shiftC;
    const int idx = blockIdx.x * 64 + threadIdx.x;
    if (idx >= B_ * C) return;
    const int b = idx >> shiftC, c = idx & (C - 1);
    const float* zp = z + (size_t)b * T_ * C + c;
    ushort* op = out + (size_t)b * T_ * C + c;

    float va[CH], vb[CH];
    float v = 0.f;
    constexpr int NCH = T_ / CH;
    static_assert(T_ % CH == 0, "chunk must divide T");

    LOADC(va, 0)
    for (int ch = 0; ch < NCH; ch += 2) {
        if (ch + 1 < NCH) { LOADC(vb, (ch + 1) * CH) }
        SCANC(va, ch * CH)
        if (ch + 2 < NCH) { LOADC(va, (ch + 2) * CH) }
        if (ch + 1 < NCH) { SCANC(vb, (ch + 1) * CH) }
    }
}
#undef LOADC
#undef SCANC

// ---------------------------------------------------------------------------
// Layer 4: wave per (b,t) row. S bf16 [9600][512], W4 f32 [10][512] in LDS.
// ---------------------------------------------------------------------------
__global__ __launch_bounds__(256) void gemm4_kernel(
    const ushort* __restrict__ S, const float* __restrict__ W4,
    float* __restrict__ out)
{
    __shared__ float W4s[10 * 512];
    for (int e = threadIdx.x; e < 5120; e += 256) W4s[e] = W4[e];
    __syncthreads();

    const int wid = (blockIdx.x * 256 + threadIdx.x) >> 6;
    const int l = threadIdx.x & 63;
    const int b = wid / T_, t = wid % T_;

    const ushort* Srow = S + (size_t)wid * 512;
    float acc[10] = {};
#pragma unroll
    for (int j = 0; j < 2; ++j) {
        ushort4 sv = *(const ushort4*)&Srow[j * 256 + l * 4];
        float s0 = bf16bits_to_f(sv.x), s1 = bf16bits_to_f(sv.y),
              s2 = bf16bits_to_f(sv.z), s3 = bf16bits_to_f(sv.w);
#pragma unroll
        for (int o = 0; o < 10; ++o) {
            float4 wv = *(const float4*)&W4s[o * 512 + j * 256 + l * 4];
            acc[o] += s0 * wv.x + s1 * wv.y + s2 * wv.z + s3 * wv.w;
        }
    }
#pragma unroll
    for (int o = 0; o < 10; ++o) {
        float v = acc[o];
        v += __shfl_xor(v, 32); v += __shfl_xor(v, 16); v += __shfl_xor(v, 8);
        v += __shfl_xor(v, 4);  v += __shfl_xor(v, 2);  v += __shfl_xor(v, 1);
        if (l == 0) out[((size_t)b * 10 + o) * T_ + t] = v;
    }
}

// ---------------------------------------------------------------------------
// Readout voltage scan: thread per (b,o), contiguous T row, in-place.
// ---------------------------------------------------------------------------
__global__ void scan4_tpn(float* __restrict__ out)
{
    int idx = blockIdx.x * 64 + threadIdx.x;
    if (idx >= B_ * 10) return;
    float* p = out + (size_t)idx * T_;
    float v = 0.f;
#pragma unroll 4
    for (int t = 0; t < T_; ++t) {
        v = ALPHA_V * v + p[t];
        p[t] = v;                          // pre-reset voltage is the output
        if (v >= TH_LAST) v = 0.f;
    }
}

extern "C" void kernel_launch(void* const* d_in, const int* in_sizes, int n_in,
                              void* d_out, int out_size, void* d_ws, size_t ws_size,
                              hipStream_t stream) {
    const float* spike = (const float*)d_in[0];   // [32, 2312, 300]
    const float* W1 = (const float*)d_in[1];      // [64, 2312]
    const float* W2 = (const float*)d_in[2];      // [512, 64]
    const float* W3 = (const float*)d_in[3];      // [512, 512]
    const float* W4 = (const float*)d_in[4];      // [10, 512]
    float* out = (float*)d_out;                   // [32, 10, 300]

    // ---- workspace layout (~52 MB)
    char* ws = (char*)d_ws;
    float*  P  = (float*)ws;                        // [4][9600][64] f32 = 9,830,400 B
    ushort* S1 = (ushort*)(ws + 9830400);           // [9600][64] bf16  = 1,228,800 B
    float*  Zf = (float*)(ws + 11059200);           // [9600][512] f32  = 19,660,800 B
    ushort* S2 = (ushort*)(ws + 30720000);          // [9600][512] bf16 = 9,830,400 B
    ushort* S3 = (ushort*)(ws + 40550400);          // [9600][512] bf16 = 9,830,400 B
    ushort* W1hi = (ushort*)(ws + 50380800);
    ushort* W1lo = W1hi + (size_t)64 * KP1;
    ushort* W2hi = W1lo + (size_t)64 * KP1;
    ushort* W2lo = W2hi + (size_t)512 * 64;
    ushort* W3hi = W2lo + (size_t)512 * 64;
    ushort* W3lo = W3hi + (size_t)512 * 512;

    // ---- weight prep (single launch)
    const int prepElems = 64 * KP1 + 512 * 64 + 512 * 512;
    prep_w_all<<<(prepElems + 255) / 256, 256, 0, stream>>>(
        W1, W1hi, W1lo, 64, CIN_, KP1,
        W2, W2hi, W2lo, 512, 64, 64,
        W3, W3hi, W3lo, 512, 512, 512);

    // ---- layer 1: fused transpose+GEMM, split-K=4; scan fuses the reduction
    gemm1_fused<<<dim3(5, 4, 32), 256, 0, stream>>>(spike, W1hi, W1lo, P);
    scan_tpn2<4, 10><<<(B_ * 64 + 63) / 64, 64, 0, stream>>>(
        P, S1, 6, (size_t)M_ * 64, TH_HID);

    // ---- layer 2 (K=64 -> 2 steps)
    gemm_mfma64<<<dim3(150, 8), 256, 0, stream>>>(S1, W2hi, W2lo, Zf, 64, 512, 2);
    scan_tpn2<1, 20><<<(B_ * 512 + 63) / 64, 64, 0, stream>>>(
        Zf, S2, 9, 0, TH_HID);

    // ---- layer 3 (K=512 -> 16 steps)
    gemm_mfma64<<<dim3(150, 8), 256, 0, stream>>>(S2, W3hi, W3lo, Zf, 512, 512, 16);
    scan_tpn2<1, 20><<<(B_ * 512 + 63) / 64, 64, 0, stream>>>(
        Zf, S3, 9, 0, TH_HID);

    // ---- layer 4 + readout scan
    gemm4_kernel<<<2400, 256, 0, stream>>>(S3, W4, out);
    scan4_tpn<<<5, 64, 0, stream>>>(out);
}

// Round 20
// 146.253 us; speedup vs baseline: 1.0266x; 1.0266x over previous
//
#include <hip/hip_runtime.h>
#include <hip/hip_bf16.h>

#define ALPHA_V 0.99f
#define TH_HID 0.1f
#define TH_LAST 1.0e5f

static constexpr int B_ = 32, T_ = 300, CIN_ = 2312;
static constexpr int KP1 = 2336;          // CIN padded to 73*32
static constexpr int M_ = 9600;           // B*T

using short8 = __attribute__((ext_vector_type(8))) short;
using f32x4  = __attribute__((ext_vector_type(4))) float;

__device__ __forceinline__ float bf16bits_to_f(ushort u) {
    union { unsigned int i; float f; } cv; cv.i = ((unsigned int)u) << 16; return cv.f;
}
__device__ __forceinline__ ushort f_to_bf16bits(float f) {
    __hip_bfloat16 h = __float2bfloat16(f);
    return *(ushort*)&h;
}

// ---------------------------------------------------------------------------
// Weight split for ALL layers in one launch: W f32 [N][K] -> Whi/Wlo bf16
// ---------------------------------------------------------------------------
__global__ void prep_w_all(
    const float* __restrict__ Wa, ushort* __restrict__ WaHi, ushort* __restrict__ WaLo, int Na, int Ka, int Kpa,
    const float* __restrict__ Wb, ushort* __restrict__ WbHi, ushort* __restrict__ WbLo, int Nb, int Kb, int Kpb,
    const float* __restrict__ Wc, ushort* __restrict__ WcHi, ushort* __restrict__ WcLo, int Nc, int Kc, int Kpc)
{
    int idx = blockIdx.x * 256 + threadIdx.x;
    const int ea = Na * Kpa, eb = Nb * Kpb, ec = Nc * Kpc;
    const float* W; ushort *Whi, *Wlo; int K, Kp;
    if (idx < ea) {
        W = Wa; Whi = WaHi; Wlo = WaLo; K = Ka; Kp = Kpa;
    } else if ((idx -= ea) < eb) {
        W = Wb; Whi = WbHi; Wlo = WbLo; K = Kb; Kp = Kpb;
    } else if ((idx -= eb) < ec) {
        W = Wc; Whi = WcHi; Wlo = WcLo; K = Kc; Kp = Kpc;
    } else return;
    int n = idx / Kp, k = idx % Kp;
    float w = (k < K) ? W[(size_t)n * K + k] : 0.f;
    __hip_bfloat16 hi = __float2bfloat16(w);
    float hif = __bfloat162float(hi);
    __hip_bfloat16 lo = __float2bfloat16(w - hif);
    Whi[idx] = *(ushort*)&hi;
    Wlo[idx] = *(ushort*)&lo;
}

// ---------------------------------------------------------------------------
// Layer-1 GEMM with FUSED transpose+bf16 convert of X.
// X f32 [B][CIN][T] (t contiguous).  P[split][b*T+t][64] f32 partials.
// Block: 64 t x 64 o tile, fixed b.  BK=32, double-buffered LDS, 4 waves 2x2.
// grid (5 t-tiles, 4 splits, 32 b).
// ---------------------------------------------------------------------------
__global__ __launch_bounds__(256) void gemm1_fused(
    const float* __restrict__ X, const ushort* __restrict__ Whi,
    const ushort* __restrict__ Wlo, float* __restrict__ P)
{
    constexpr int LP = 40;
    __shared__ ushort As[2][64 * LP];
    __shared__ ushort Bh[2][64 * LP];
    __shared__ ushort Bl[2][64 * LP];

    const int tid = threadIdx.x;
    const int t0 = blockIdx.x * 64;
    const int split = blockIdx.y;
    const int b = blockIdx.z;
    const int stepBeg = split * 19;                 // 73 steps: 19/19/19/16
    const int nSteps = min(19, 73 - stepBeg);
    const int tvalid = min(64, T_ - t0);
    float* Z = P + (size_t)split * M_ * 64;

    const int wid = tid >> 6, lane = tid & 63;
    const int wm = (wid >> 1) * 32, wn = (wid & 1) * 32;
    const int lr = lane & 15, lk = (lane >> 4) * 8;

    f32x4 acc[2][2];
    {
        f32x4 z4 = {0.f, 0.f, 0.f, 0.f};
        acc[0][0] = z4; acc[0][1] = z4; acc[1][0] = z4; acc[1][1] = z4;
    }

    const int p = tid >> 4;                         // k-pair 0..15
    const int tq = tid & 15;                        // t-quad
    const bool tok = (tq * 4 < tvalid);
    const float* Xb = X + (size_t)b * CIN_ * T_ + t0 + tq * 4;

    const int sr = tid >> 2, sq = (tid & 3) * 8;
    const ushort* Hp = Whi + (size_t)sr * KP1 + (size_t)stepBeg * 32 + sq;
    const ushort* Lp = Wlo + (size_t)sr * KP1 + (size_t)stepBeg * 32 + sq;
    const int sdstW = sr * LP + sq;

    f32x4 xa, xb;
    uint4 rh, rl;

    auto loadStep = [&](int s) {
        int gk = (stepBeg + s) * 32 + 2 * p;
        f32x4 z4 = {0.f, 0.f, 0.f, 0.f};
        xa = z4; xb = z4;
        if (tok) {
            if (gk < CIN_)     xa = *(const f32x4*)&Xb[(size_t)gk * T_];
            if (gk + 1 < CIN_) xb = *(const f32x4*)&Xb[(size_t)(gk + 1) * T_];
        }
        rh = *(const uint4*)(Hp + (size_t)s * 32);
        rl = *(const uint4*)(Lp + (size_t)s * 32);
    };
    auto writeStep = [&](int bufi) {
#pragma unroll
        for (int j = 0; j < 4; ++j) {
            uint u = (uint)f_to_bf16bits(xa[j]) | ((uint)f_to_bf16bits(xb[j]) << 16);
            *(uint*)&As[bufi][(tq * 4 + j) * LP + 2 * p] = u;
        }
        *(uint4*)&Bh[bufi][sdstW] = rh;
        *(uint4*)&Bl[bufi][sdstW] = rl;
    };

    loadStep(0);
    writeStep(0);
    for (int s = 0; s < nSteps; ++s) {
        const int cur = s & 1, nxt = cur ^ 1;
        if (s + 1 < nSteps) loadStep(s + 1);        // global loads overlap barrier+MFMA
        __syncthreads();                            // buf[cur] visible

        short8 af[2], bhf[2], blf[2];
#pragma unroll
        for (int i = 0; i < 2; ++i) {
            af[i]  = *(const short8*)&As[cur][(wm + i * 16 + lr) * LP + lk];
            bhf[i] = *(const short8*)&Bh[cur][(wn + i * 16 + lr) * LP + lk];
            blf[i] = *(const short8*)&Bl[cur][(wn + i * 16 + lr) * LP + lk];
        }
#pragma unroll
        for (int i = 0; i < 2; ++i)
#pragma unroll
            for (int j = 0; j < 2; ++j) {
                acc[i][j] = __builtin_amdgcn_mfma_f32_16x16x32_bf16(af[i], bhf[j], acc[i][j], 0, 0, 0);
                acc[i][j] = __builtin_amdgcn_mfma_f32_16x16x32_bf16(af[i], blf[j], acc[i][j], 0, 0, 0);
            }
        if (s + 1 < nSteps) writeStep(nxt);
    }

    // C/D: col = lane&15, row = (lane>>4)*4 + r
    const int orow = (lane >> 4) * 4;
#pragma unroll
    for (int i = 0; i < 2; ++i)
#pragma unroll
        for (int j = 0; j < 2; ++j)
#pragma unroll
            for (int r = 0; r < 4; ++r) {
                int tl = wm + i * 16 + orow + r;
                if (tl < tvalid)
                    Z[(size_t)(b * T_ + t0 + tl) * 64 + (wn + j * 16 + lr)] = acc[i][j][r];
            }
}

// ---------------------------------------------------------------------------
// MFMA GEMM 64x64 tile, BK=32, double-buffered LDS (layers 2, 3).
// Separate-kernel structure beats GEMM+scan fusion here (R15: 1 blk/CU
// 152KB-LDS fusion +8us; R16: 2 blk/CU OT=32 fusion +7us): 1200 blocks
// run flat-out, and the Zf round-trip is cheaper than the exposed latency
// of in-block GEMM->scan serialization.
// ---------------------------------------------------------------------------
__global__ __launch_bounds__(256) void gemm_mfma64(
    const ushort* __restrict__ A, const ushort* __restrict__ Whi,
    const ushort* __restrict__ Wlo, float* __restrict__ Z,
    int lda, int ldz, int nSteps)
{
    constexpr int LP = 40;
    __shared__ ushort As[2][64 * LP];
    __shared__ ushort Bh[2][64 * LP];
    __shared__ ushort Bl[2][64 * LP];

    const int tid = threadIdx.x;
    const int m0 = blockIdx.x * 64, n0 = blockIdx.y * 64;

    const int wid = tid >> 6, lane = tid & 63;
    const int wm = (wid >> 1) * 32, wn = (wid & 1) * 32;
    const int lr = lane & 15, lk = (lane >> 4) * 8;

    f32x4 acc[2][2];
    {
        f32x4 z4 = {0.f, 0.f, 0.f, 0.f};
        acc[0][0] = z4; acc[0][1] = z4; acc[1][0] = z4; acc[1][1] = z4;
    }

    const int sr = tid >> 2, sq = (tid & 3) * 8;
    const ushort* Ap = A   + (size_t)(m0 + sr) * lda + sq;
    const ushort* Hp = Whi + (size_t)(n0 + sr) * lda + sq;
    const ushort* Lp = Wlo + (size_t)(n0 + sr) * lda + sq;
    const int sdst = sr * LP + sq;

    uint4 ra = *(const uint4*)(Ap);
    uint4 rh = *(const uint4*)(Hp);
    uint4 rl = *(const uint4*)(Lp);
    *(uint4*)&As[0][sdst] = ra;
    *(uint4*)&Bh[0][sdst] = rh;
    *(uint4*)&Bl[0][sdst] = rl;

    for (int s = 0; s < nSteps; ++s) {
        const int cur = s & 1, nxt = cur ^ 1;
        if (s + 1 < nSteps) {
            ra = *(const uint4*)(Ap + (size_t)(s + 1) * 32);
            rh = *(const uint4*)(Hp + (size_t)(s + 1) * 32);
            rl = *(const uint4*)(Lp + (size_t)(s + 1) * 32);
        }
        __syncthreads();

        short8 af[2], bhf[2], blf[2];
#pragma unroll
        for (int i = 0; i < 2; ++i) {
            af[i]  = *(const short8*)&As[cur][(wm + i * 16 + lr) * LP + lk];
            bhf[i] = *(const short8*)&Bh[cur][(wn + i * 16 + lr) * LP + lk];
            blf[i] = *(const short8*)&Bl[cur][(wn + i * 16 + lr) * LP + lk];
        }
#pragma unroll
        for (int i = 0; i < 2; ++i)
#pragma unroll
            for (int j = 0; j < 2; ++j) {
                acc[i][j] = __builtin_amdgcn_mfma_f32_16x16x32_bf16(af[i], bhf[j], acc[i][j], 0, 0, 0);
                acc[i][j] = __builtin_amdgcn_mfma_f32_16x16x32_bf16(af[i], blf[j], acc[i][j], 0, 0, 0);
            }
        if (s + 1 < nSteps) {
            *(uint4*)&As[nxt][sdst] = ra;
            *(uint4*)&Bh[nxt][sdst] = rh;
            *(uint4*)&Bl[nxt][sdst] = rl;
        }
    }

    const int orow = (lane >> 4) * 4;
#pragma unroll
    for (int i = 0; i < 2; ++i)
#pragma unroll
        for (int j = 0; j < 2; ++j)
#pragma unroll
            for (int r = 0; r < 4; ++r)
                Z[(size_t)(m0 + wm + i * 16 + orow + r) * ldz + (n0 + wn + j * 16 + lr)]
                    = acc[i][j][r];
}

// ---------------------------------------------------------------------------
// CUBA-LIF scan, thread per neuron, chunked register double-buffer prefetch.
// CH=10 is the measured optimum (R8/R14/R18: 147us total).  Falsified
// alternatives: CH=20/25 runtime loop (R10: 62us/scan), CH=20/30 fully
// unrolled (R11: 105us/scan), CH=20 + __launch_bounds__(64,1) (R19: +3us).
// ---------------------------------------------------------------------------
#define LOADC(buf, t0)                                                       \
    _Pragma("unroll")                                                        \
    for (int j = 0; j < CH; ++j) {                                           \
        float sacc = zp[(size_t)((t0) + j) * C];                             \
        _Pragma("unroll")                                                    \
        for (int k = 1; k < NS; ++k)                                         \
            sacc += zp[(size_t)k * splitStride + (size_t)((t0) + j) * C];    \
        buf[j] = sacc;                                                       \
    }
#define SCANC(buf, t0)                                                       \
    _Pragma("unroll")                                                        \
    for (int j = 0; j < CH; ++j) {                                           \
        v = ALPHA_V * v + buf[j];                                            \
        bool sp = (v >= th);                                                 \
        op[(size_t)((t0) + j) * C] = sp ? (ushort)0x3F80 : (ushort)0;        \
        v = sp ? 0.f : v;                                                    \
    }

template<int NS, int CH>
__global__ __launch_bounds__(64) void scan_tpn2(
    const float* __restrict__ z, ushort* __restrict__ out,
    int shiftC, size_t splitStride, float th)
{
    const int C = 1 << shiftC;
    const int idx = blockIdx.x * 64 + threadIdx.x;
    if (idx >= B_ * C) return;
    const int b = idx >> shiftC, c = idx & (C - 1);
    const float* zp = z + (size_t)b * T_ * C + c;
    ushort* op = out + (size_t)b * T_ * C + c;

    float va[CH], vb[CH];
    float v = 0.f;
    constexpr int NCH = T_ / CH;
    static_assert(T_ % CH == 0, "chunk must divide T");

    LOADC(va, 0)
    for (int ch = 0; ch < NCH; ch += 2) {
        if (ch + 1 < NCH) { LOADC(vb, (ch + 1) * CH) }
        SCANC(va, ch * CH)
        if (ch + 2 < NCH) { LOADC(va, (ch + 2) * CH) }
        if (ch + 1 < NCH) { SCANC(vb, (ch + 1) * CH) }
    }
}
#undef LOADC
#undef SCANC

// ---------------------------------------------------------------------------
// Layer 4: wave per (b,t) row. S bf16 [9600][512], W4 f32 [10][512] in LDS.
// ---------------------------------------------------------------------------
__global__ __launch_bounds__(256) void gemm4_kernel(
    const ushort* __restrict__ S, const float* __restrict__ W4,
    float* __restrict__ out)
{
    __shared__ float W4s[10 * 512];
    for (int e = threadIdx.x; e < 5120; e += 256) W4s[e] = W4[e];
    __syncthreads();

    const int wid = (blockIdx.x * 256 + threadIdx.x) >> 6;
    const int l = threadIdx.x & 63;
    const int b = wid / T_, t = wid % T_;

    const ushort* Srow = S + (size_t)wid * 512;
    float acc[10] = {};
#pragma unroll
    for (int j = 0; j < 2; ++j) {
        ushort4 sv = *(const ushort4*)&Srow[j * 256 + l * 4];
        float s0 = bf16bits_to_f(sv.x), s1 = bf16bits_to_f(sv.y),
              s2 = bf16bits_to_f(sv.z), s3 = bf16bits_to_f(sv.w);
#pragma unroll
        for (int o = 0; o < 10; ++o) {
            float4 wv = *(const float4*)&W4s[o * 512 + j * 256 + l * 4];
            acc[o] += s0 * wv.x + s1 * wv.y + s2 * wv.z + s3 * wv.w;
        }
    }
#pragma unroll
    for (int o = 0; o < 10; ++o) {
        float v = acc[o];
        v += __shfl_xor(v, 32); v += __shfl_xor(v, 16); v += __shfl_xor(v, 8);
        v += __shfl_xor(v, 4);  v += __shfl_xor(v, 2);  v += __shfl_xor(v, 1);
        if (l == 0) out[((size_t)b * 10 + o) * T_ + t] = v;
    }
}

// ---------------------------------------------------------------------------
// Readout voltage scan: thread per (b,o), contiguous T row, in-place.
// ---------------------------------------------------------------------------
__global__ void scan4_tpn(float* __restrict__ out)
{
    int idx = blockIdx.x * 64 + threadIdx.x;
    if (idx >= B_ * 10) return;
    float* p = out + (size_t)idx * T_;
    float v = 0.f;
#pragma unroll 4
    for (int t = 0; t < T_; ++t) {
        v = ALPHA_V * v + p[t];
        p[t] = v;                          // pre-reset voltage is the output
        if (v >= TH_LAST) v = 0.f;
    }
}

extern "C" void kernel_launch(void* const* d_in, const int* in_sizes, int n_in,
                              void* d_out, int out_size, void* d_ws, size_t ws_size,
                              hipStream_t stream) {
    const float* spike = (const float*)d_in[0];   // [32, 2312, 300]
    const float* W1 = (const float*)d_in[1];      // [64, 2312]
    const float* W2 = (const float*)d_in[2];      // [512, 64]
    const float* W3 = (const float*)d_in[3];      // [512, 512]
    const float* W4 = (const float*)d_in[4];      // [10, 512]
    float* out = (float*)d_out;                   // [32, 10, 300]

    // ---- workspace layout (~52 MB)
    char* ws = (char*)d_ws;
    float*  P  = (float*)ws;                        // [4][9600][64] f32 = 9,830,400 B
    ushort* S1 = (ushort*)(ws + 9830400);           // [9600][64] bf16  = 1,228,800 B
    float*  Zf = (float*)(ws + 11059200);           // [9600][512] f32  = 19,660,800 B
    ushort* S2 = (ushort*)(ws + 30720000);          // [9600][512] bf16 = 9,830,400 B
    ushort* S3 = (ushort*)(ws + 40550400);          // [9600][512] bf16 = 9,830,400 B
    ushort* W1hi = (ushort*)(ws + 50380800);
    ushort* W1lo = W1hi + (size_t)64 * KP1;
    ushort* W2hi = W1lo + (size_t)64 * KP1;
    ushort* W2lo = W2hi + (size_t)512 * 64;
    ushort* W3hi = W2lo + (size_t)512 * 64;
    ushort* W3lo = W3hi + (size_t)512 * 512;

    // ---- weight prep (single launch)
    const int prepElems = 64 * KP1 + 512 * 64 + 512 * 512;
    prep_w_all<<<(prepElems + 255) / 256, 256, 0, stream>>>(
        W1, W1hi, W1lo, 64, CIN_, KP1,
        W2, W2hi, W2lo, 512, 64, 64,
        W3, W3hi, W3lo, 512, 512, 512);

    // ---- layer 1: fused transpose+GEMM, split-K=4; scan fuses the reduction
    gemm1_fused<<<dim3(5, 4, 32), 256, 0, stream>>>(spike, W1hi, W1lo, P);
    scan_tpn2<4, 10><<<(B_ * 64 + 63) / 64, 64, 0, stream>>>(
        P, S1, 6, (size_t)M_ * 64, TH_HID);

    // ---- layer 2 (K=64 -> 2 steps)
    gemm_mfma64<<<dim3(150, 8), 256, 0, stream>>>(S1, W2hi, W2lo, Zf, 64, 512, 2);
    scan_tpn2<1, 10><<<(B_ * 512 + 63) / 64, 64, 0, stream>>>(
        Zf, S2, 9, 0, TH_HID);

    // ---- layer 3 (K=512 -> 16 steps)
    gemm_mfma64<<<dim3(150, 8), 256, 0, stream>>>(S2, W3hi, W3lo, Zf, 512, 512, 16);
    scan_tpn2<1, 10><<<(B_ * 512 + 63) / 64, 64, 0, stream>>>(
        Zf, S3, 9, 0, TH_HID);

    // ---- layer 4 + readout scan
    gemm4_kernel<<<2400, 256, 0, stream>>>(S3, W4, out);
    scan4_tpn<<<5, 64, 0, stream>>>(out);
}